// Round 4
// baseline (190.669 us; speedup 1.0000x reference)
//
#include <hip/hip_runtime.h>

#define BATCH 65536
#define MT 128                // rows per block

typedef unsigned short u16;
typedef __bf16 bf16x8 __attribute__((ext_vector_type(8)));
typedef float f32x4 __attribute__((ext_vector_type(4)));

// d_ws layout (u16 element offsets) — fragment-native weight layouts:
//   W'[K32][col][g][e]: element (col, k) at [K32][col][k>>3 & 3][k&7], k = K32*32+g*8+e
#define WI_OFF 0              // [1][512][4][8]   (k>=16 zero)
#define WH_OFF 16384          // [2][16][512][4][8]
#define WO_OFF 540672         // [16][32][4][8]   (cols o padded 17->32)
#define WS_USH 557056
// float region at (char*)ws + WS_USH*2
#define BI_F 0
#define BH_F 512
#define BO_F 1536
#define ERR_F 1568
#define PREP_WH 65536
#define PREP_WI 2048
#define PREP_WO 2048
#define PREP_SC 1570
#define PREP_TOTAL (PREP_WH + PREP_WI + PREP_WO + PREP_SC)

__device__ inline u16 f2bf(float f) {
  union { float f; unsigned u; } v; v.f = f;
  unsigned u = v.u + 0x7fffu + ((v.u >> 16) & 1u);   // RNE
  return (u16)(u >> 16);
}

__global__ void prep_kernel(const float* __restrict__ w_in, const float* __restrict__ b_in,
                            const float* __restrict__ w_hid, const float* __restrict__ b_hid,
                            const float* __restrict__ w_out, const float* __restrict__ b_out,
                            const int* __restrict__ variant, int n,
                            u16* __restrict__ wsu, float* __restrict__ wsf)
{
  const int model = (n - 5) * 16 + variant[0];
  const int i = blockIdx.x * 256 + threadIdx.x;
  if (i < PREP_WH) {
    int g = i & 3, col = (i >> 2) & 511, K32 = (i >> 11) & 15, l = i >> 15;
    const float* src = w_hid + (size_t)model * 524288 + (size_t)l * 262144 + col * 512 + K32 * 32 + g * 8;
    u16* dst = wsu + WH_OFF + (size_t)i * 8;
    #pragma unroll
    for (int e = 0; e < 8; ++e) dst[e] = f2bf(src[e]);
  } else if (i < PREP_WH + PREP_WI) {
    int j = i - PREP_WH;
    int g = j & 3, col = j >> 2;
    u16* dst = wsu + WI_OFF + (size_t)j * 8;
    #pragma unroll
    for (int e = 0; e < 8; ++e) {
      int k = g * 8 + e;
      dst[e] = (k < 16) ? f2bf(w_in[(size_t)model * 8192 + col * 16 + k]) : (u16)0;
    }
  } else if (i < PREP_WH + PREP_WI + PREP_WO) {
    int j = i - PREP_WH - PREP_WI;
    int g = j & 3, col = (j >> 2) & 31, K32 = j >> 7;
    u16* dst = wsu + WO_OFF + (size_t)j * 8;
    #pragma unroll
    for (int e = 0; e < 8; ++e) {
      int k = K32 * 32 + g * 8 + e;
      dst[e] = (col < 17) ? f2bf(w_out[(size_t)model * 8704 + col * 512 + k]) : (u16)0;
    }
  } else if (i < PREP_TOTAL) {
    int j = i - PREP_WH - PREP_WI - PREP_WO;
    if (j < 512)       wsf[BI_F + j] = b_in[(size_t)model * 512 + j];
    else if (j < 1536) wsf[BH_F + (j - 512)] = b_hid[(size_t)model * 1024 + (j - 512)];
    else if (j < 1568) { int o = j - 1536; wsf[BO_F + o] = (o < 17) ? b_out[(size_t)model * 17 + o] : 0.f; }
    else               wsf[ERR_F + (j - 1568)] = 0.f;
  }
}

// xs layout: byte = row*1024 + ((col*2) ^ ((row&15)<<4))
__device__ __forceinline__ bf16x8 rdA(const char* xb, int row, int kbyte) {
  return *reinterpret_cast<const bf16x8*>(xb + row * 1024 + (kbyte ^ ((row & 15) << 4)));
}
__device__ __forceinline__ void st16(char* xb, int row, int col, u16 v) {
  *(u16*)(xb + row * 1024 + ((col * 2) ^ ((row & 15) << 4))) = v;
}

// One dense layer slice: wave computes rows [r0,r0+64) x cols [c0,c0+64).
// NK: compile-time K32 step count (power of 2). koff: per-block K-phase stagger.
template<int NK>
__device__ __forceinline__ void dense_layer(const u16* __restrict__ Wp,
                                            const float* __restrict__ bias, int act,
                                            char* xb, int l15, int q, int r0, int c0, int koff)
{
  f32x4 acc[4][4];
  #pragma unroll
  for (int a = 0; a < 4; ++a)
    #pragma unroll
    for (int b = 0; b < 4; ++b) { f32x4 z = {0.f, 0.f, 0.f, 0.f}; acc[a][b] = z; }

  const u16* Wl = Wp + (c0 + l15) * 32 + q * 8;   // lane's base within a K32 block
  uint4 b0[4], b1[4];
  {
    const u16* p = Wl + (size_t)((koff) & (NK - 1)) * 16384;
    #pragma unroll
    for (int ct = 0; ct < 4; ++ct)
      b0[ct] = *reinterpret_cast<const uint4*>(p + ct * 512);
  }

  #pragma unroll
  for (int i = 0; i < NK; i += 2) {
    if (i + 1 < NK) {
      const u16* p = Wl + (size_t)((i + 1 + koff) & (NK - 1)) * 16384;
      #pragma unroll
      for (int ct = 0; ct < 4; ++ct)
        b1[ct] = *reinterpret_cast<const uint4*>(p + ct * 512);
    }
    {
      const int kb = ((i + koff) & (NK - 1)) * 64 + q * 16;
      #pragma unroll
      for (int mt = 0; mt < 4; ++mt) {
        bf16x8 a = rdA(xb, r0 + mt * 16 + l15, kb);
        #pragma unroll
        for (int ct = 0; ct < 4; ++ct)
          acc[mt][ct] = __builtin_amdgcn_mfma_f32_16x16x32_bf16(
              a, __builtin_bit_cast(bf16x8, b0[ct]), acc[mt][ct], 0, 0, 0);
      }
    }
    if (i + 1 < NK) {
      if (i + 2 < NK) {
        const u16* p = Wl + (size_t)((i + 2 + koff) & (NK - 1)) * 16384;
        #pragma unroll
        for (int ct = 0; ct < 4; ++ct)
          b0[ct] = *reinterpret_cast<const uint4*>(p + ct * 512);
      }
      const int kb = ((i + 1 + koff) & (NK - 1)) * 64 + q * 16;
      #pragma unroll
      for (int mt = 0; mt < 4; ++mt) {
        bf16x8 a = rdA(xb, r0 + mt * 16 + l15, kb);
        #pragma unroll
        for (int ct = 0; ct < 4; ++ct)
          acc[mt][ct] = __builtin_amdgcn_mfma_f32_16x16x32_bf16(
              a, __builtin_bit_cast(bf16x8, b1[ct]), acc[mt][ct], 0, 0, 0);
      }
    }
  }
  __syncthreads();   // all waves done READING xs

  float bv[4];
  #pragma unroll
  for (int ct = 0; ct < 4; ++ct) bv[ct] = bias[c0 + ct * 16 + l15];
  #pragma unroll
  for (int mt = 0; mt < 4; ++mt)
    #pragma unroll
    for (int ct = 0; ct < 4; ++ct)
      #pragma unroll
      for (int j = 0; j < 4; ++j) {
        int row = r0 + mt * 16 + q * 4 + j;
        float z = acc[mt][ct][j] + bv[ct];
        float h = act ? fmaxf(z, 0.f) : z / (1.f + __expf(-z));
        st16(xb, row, c0 + ct * 16 + l15, f2bf(h));
      }
  __syncthreads();   // xs updated for next layer
}

template<int CN>
__global__ __launch_bounds__(1024, 4) void fused_kernel(
    const float* __restrict__ T, const u16* __restrict__ wsu,
    const float* __restrict__ wsf, float* __restrict__ Xout, float* __restrict__ Xcout,
    float* __restrict__ errAcc, int n_arg)
{
  const int n = CN ? CN : n_arg;
  __shared__ u16 xs[MT * 512];       // 128 KiB, XOR-swizzled
  __shared__ float xo[MT * 20];      // X_hat rows for distortion
  __shared__ float scaleS[MT];
  __shared__ float ered[16][2];

  const int tid = threadIdx.x;
  const int blk = blockIdx.x;
  const int lane = tid & 63;
  const int wid = tid >> 6;          // 0..15
  const int l15 = lane & 15;
  const int q = lane >> 4;           // 0..3
  const int r0 = (wid >> 3) * 64;    // wave's row base: 0 or 64
  const int c0 = (wid & 7) * 64;     // wave's col base: 0..448
  const int koff = (blk >> 3) & 15;  // K-phase stagger (co-resident blocks differ)
  char* xb = (char*)xs;

  // ---- prologue: T load + normalize; 8 threads/row ----
  {
    const int r = tid >> 3, j = tid & 7;
    const size_t gr = (size_t)blk * MT + r;
    const float* tp = T + gr * n;
    const int k0 = 2 * j, k1 = 2 * j + 1;
    float v0 = (k0 < n) ? tp[k0] : 0.f;
    float v1 = (k1 < n) ? tp[k1] : 0.f;
    float ss = v0 * v0 + v1 * v1;
    ss += __shfl_xor(ss, 1); ss += __shfl_xor(ss, 2); ss += __shfl_xor(ss, 4);
    float norm = sqrtf(ss < 1e-12f ? 1e-12f : ss);
    float rn = 1.f / norm;
    if (j == 0) scaleS[r] = sqrtf(norm);
    st16(xb, r, k0, f2bf(v0 * rn));
    st16(xb, r, k1, f2bf(v1 * rn));
    st16(xb, r, 16 + k0, 0);
    st16(xb, r, 16 + k1, 0);
  }
  __syncthreads();

  dense_layer<1 >(wsu + WI_OFF,          wsf + BI_F,       0, xb, l15, q, r0, c0, 0);
  dense_layer<16>(wsu + WH_OFF,          wsf + BH_F,       1, xb, l15, q, r0, c0, koff);
  dense_layer<16>(wsu + WH_OFF + 262144, wsf + BH_F + 512, 1, xb, l15, q, r0, c0, koff);

  // ---- output layer: waves 0..7, wave w owns rows w*16..+16, 32 padded cols ----
  if (wid < 8) {
    f32x4 oacc[2];
    { f32x4 z = {0.f, 0.f, 0.f, 0.f}; oacc[0] = z; oacc[1] = z; }
    const int bofs2 = l15 * 32 + q * 8;
    uint4 ob[2], on[2];
    #pragma unroll
    for (int ct = 0; ct < 2; ++ct)
      ob[ct] = *reinterpret_cast<const uint4*>(wsu + WO_OFF + bofs2 + ct * 512);
    #pragma unroll
    for (int K2 = 0; K2 < 16; K2 += 2) {
      #pragma unroll
      for (int ct = 0; ct < 2; ++ct)
        on[ct] = *reinterpret_cast<const uint4*>(wsu + WO_OFF + (K2 + 1) * 1024 + bofs2 + ct * 512);
      {
        bf16x8 a = rdA(xb, wid * 16 + l15, K2 * 64 + q * 16);
        #pragma unroll
        for (int ct = 0; ct < 2; ++ct)
          oacc[ct] = __builtin_amdgcn_mfma_f32_16x16x32_bf16(
              a, __builtin_bit_cast(bf16x8, ob[ct]), oacc[ct], 0, 0, 0);
      }
      if (K2 + 2 < 16) {
        #pragma unroll
        for (int ct = 0; ct < 2; ++ct)
          ob[ct] = *reinterpret_cast<const uint4*>(wsu + WO_OFF + (K2 + 2) * 1024 + bofs2 + ct * 512);
      }
      {
        bf16x8 a = rdA(xb, wid * 16 + l15, (K2 + 1) * 64 + q * 16);
        #pragma unroll
        for (int ct = 0; ct < 2; ++ct)
          oacc[ct] = __builtin_amdgcn_mfma_f32_16x16x32_bf16(
              a, __builtin_bit_cast(bf16x8, on[ct]), oacc[ct], 0, 0, 0);
      }
    }
    #pragma unroll
    for (int ct = 0; ct < 2; ++ct)
      #pragma unroll
      for (int j = 0; j < 4; ++j) {
        int o = ct * 16 + l15;
        int row = wid * 16 + q * 4 + j;
        if (o <= n) {
          float val = (oacc[ct][j] + wsf[BO_F + o]) * scaleS[row];
          size_t gr = (size_t)blk * MT + row;
          float cv = fminf(fmaxf(val, -2.f), 2.f);
          Xout[gr * (n + 1) + o] = val;
          Xcout[gr * (n + 1) + o] = cv;
          xo[row * 20 + o] = val;
        }
      }
  }
  __syncthreads();

  // ---- distortion + squared-error partials: 8 threads/row ----
  {
    const int r = tid >> 3, j = tid & 7;
    const size_t gr = (size_t)blk * MT + r;
    float x[17], cx[17];
    #pragma unroll
    for (int i = 0; i < 17; ++i) {
      float v = (i <= n) ? xo[r * 20 + i] : 0.f;
      x[i] = v; cx[i] = fminf(fmaxf(v, -2.f), 2.f);
    }
    float e = 0.f, ec = 0.f;
    #pragma unroll
    for (int kk = 0; kk < 2; ++kk) {
      int k = j + 1 + kk * 8;
      if (k <= n) {
        float d = 0.f, dc = 0.f;
        #pragma unroll
        for (int i = 0; i < 16; ++i) {
          if (i + k <= 16) {
            if (i + k <= n) { d += x[i] * x[i + k]; dc += cx[i] * cx[i + k]; }
          }
        }
        float tvv = T[gr * n + (n - k)];
        float r1 = d - tvv, r2 = dc - tvv;
        e += r1 * r1; ec += r2 * r2;
      }
    }
    e += __shfl_xor(e, 1);  ec += __shfl_xor(ec, 1);
    e += __shfl_xor(e, 2);  ec += __shfl_xor(ec, 2);
    e += __shfl_xor(e, 4);  ec += __shfl_xor(ec, 4);
    e += __shfl_xor(e, 8);  ec += __shfl_xor(ec, 8);
    e += __shfl_xor(e, 16); ec += __shfl_xor(ec, 16);
    e += __shfl_xor(e, 32); ec += __shfl_xor(ec, 32);
    if (lane == 0) { ered[wid][0] = e; ered[wid][1] = ec; }
  }
  __syncthreads();
  if (tid == 0) {
    float e = 0.f, ec = 0.f;
    #pragma unroll
    for (int w = 0; w < 16; ++w) { e += ered[w][0]; ec += ered[w][1]; }
    atomicAdd(&errAcc[0], e);
    atomicAdd(&errAcc[1], ec);
  }
}

__global__ void finalize_kernel(const float* __restrict__ errAcc, float* __restrict__ e0,
                                float* __restrict__ e1, float inv)
{
  e0[0] = errAcc[0] * inv;
  e1[0] = errAcc[1] * inv;
}

extern "C" void kernel_launch(void* const* d_in, const int* in_sizes, int n_in,
                              void* d_out, int out_size, void* d_ws, size_t ws_size,
                              hipStream_t stream)
{
  const float* T       = (const float*)d_in[0];
  const int*   variant = (const int*)d_in[2];
  const float* w_in    = (const float*)d_in[3];
  const float* b_in    = (const float*)d_in[4];
  const float* w_hid   = (const float*)d_in[5];
  const float* b_hid   = (const float*)d_in[6];
  const float* w_out   = (const float*)d_in[7];
  const float* b_out   = (const float*)d_in[8];
  const int n = in_sizes[0] / BATCH;

  u16* wsu = (u16*)d_ws;
  float* wsf = (float*)((char*)d_ws + (size_t)WS_USH * 2);
  float* out = (float*)d_out;
  const size_t xe = (size_t)BATCH * (n + 1);
  float* Xo  = out;
  float* eP  = out + xe;
  float* Xc  = out + xe + 1;
  float* ecP = out + 2 * xe + 1;

  const int prepBlocks = (PREP_TOTAL + 255) / 256;
  prep_kernel<<<prepBlocks, 256, 0, stream>>>(w_in, b_in, w_hid, b_hid, w_out, b_out,
                                              variant, n, wsu, wsf);
  if (n == 16)
    fused_kernel<16><<<BATCH / MT, 1024, 0, stream>>>(T, wsu, wsf, Xo, Xc, wsf + ERR_F, n);
  else
    fused_kernel<0><<<BATCH / MT, 1024, 0, stream>>>(T, wsu, wsf, Xo, Xc, wsf + ERR_F, n);
  finalize_kernel<<<1, 1, 0, stream>>>(wsf + ERR_F, eP, ecP, 1.f / (float)((size_t)BATCH * n));
}

// Round 5
// 145.582 us; speedup vs baseline: 1.3097x; 1.3097x over previous
//
#include <hip/hip_runtime.h>

#define BATCH 65536
#define MT 64                 // rows per block

typedef unsigned short u16;
typedef __bf16 bf16x8 __attribute__((ext_vector_type(8)));
typedef float f32x4 __attribute__((ext_vector_type(4)));

// d_ws layout (u16 element offsets) — fragment-native weight layouts:
//   W'[K32][col][g][e]: element (col, k) at [K32][col][k>>3 & 3][k&7], k = K32*32+g*8+e
#define WI_OFF 0              // [1][512][4][8]   (k>=16 zero)
#define WH_OFF 16384          // [2][16][512][4][8]
#define WO_OFF 540672         // [16][32][4][8]   (cols o padded 17->32)
#define WS_USH 557056
// float region at (char*)ws + WS_USH*2
#define BI_F 0
#define BH_F 512
#define BO_F 1536
#define PART_F 1568           // [1024][2] per-block error partials
#define PREP_WH 65536
#define PREP_WI 2048
#define PREP_WO 2048
#define PREP_SC 1568
#define PREP_TOTAL (PREP_WH + PREP_WI + PREP_WO + PREP_SC)

__device__ inline u16 f2bf(float f) {
  union { float f; unsigned u; } v; v.f = f;
  unsigned u = v.u + 0x7fffu + ((v.u >> 16) & 1u);   // RNE
  return (u16)(u >> 16);
}

__global__ void prep_kernel(const float* __restrict__ w_in, const float* __restrict__ b_in,
                            const float* __restrict__ w_hid, const float* __restrict__ b_hid,
                            const float* __restrict__ w_out, const float* __restrict__ b_out,
                            const int* __restrict__ variant, int n,
                            u16* __restrict__ wsu, float* __restrict__ wsf)
{
  const int model = (n - 5) * 16 + variant[0];
  const int i = blockIdx.x * 256 + threadIdx.x;
  if (i < PREP_WH) {
    int g = i & 3, col = (i >> 2) & 511, K32 = (i >> 11) & 15, l = i >> 15;
    const float* src = w_hid + (size_t)model * 524288 + (size_t)l * 262144 + col * 512 + K32 * 32 + g * 8;
    u16* dst = wsu + WH_OFF + (size_t)i * 8;
    #pragma unroll
    for (int e = 0; e < 8; ++e) dst[e] = f2bf(src[e]);
  } else if (i < PREP_WH + PREP_WI) {
    int j = i - PREP_WH;
    int g = j & 3, col = j >> 2;
    u16* dst = wsu + WI_OFF + (size_t)j * 8;
    #pragma unroll
    for (int e = 0; e < 8; ++e) {
      int k = g * 8 + e;
      dst[e] = (k < 16) ? f2bf(w_in[(size_t)model * 8192 + col * 16 + k]) : (u16)0;
    }
  } else if (i < PREP_WH + PREP_WI + PREP_WO) {
    int j = i - PREP_WH - PREP_WI;
    int g = j & 3, col = (j >> 2) & 31, K32 = j >> 7;
    u16* dst = wsu + WO_OFF + (size_t)j * 8;
    #pragma unroll
    for (int e = 0; e < 8; ++e) {
      int k = K32 * 32 + g * 8 + e;
      dst[e] = (col < 17) ? f2bf(w_out[(size_t)model * 8704 + col * 512 + k]) : (u16)0;
    }
  } else if (i < PREP_TOTAL) {
    int j = i - PREP_WH - PREP_WI - PREP_WO;
    if (j < 512)       wsf[BI_F + j] = b_in[(size_t)model * 512 + j];
    else if (j < 1536) wsf[BH_F + (j - 512)] = b_hid[(size_t)model * 1024 + (j - 512)];
    else               { int o = j - 1536; wsf[BO_F + o] = (o < 17) ? b_out[(size_t)model * 17 + o] : 0.f; }
  }
}

// xs layout: byte = row*1024 + ((col*2) ^ ((row&15)<<4))
__device__ __forceinline__ bf16x8 rdA(const char* xb, int row, int kbyte) {
  return *reinterpret_cast<const bf16x8*>(xb + row * 1024 + (kbyte ^ ((row & 15) << 4)));
}
__device__ __forceinline__ void st16(char* xb, int row, int col, u16 v) {
  *(u16*)(xb + row * 1024 + ((col * 2) ^ ((row & 15) << 4))) = v;
}

// One dense layer: wave computes rows [0,64) x cols [c0,c0+64), B direct from global.
// NK: compile-time K32 step count. koff: per-block K-phase (XOR stagger). act: 0=silu 1=relu.
template<int NK>
__device__ __forceinline__ void dense_layer(const u16* __restrict__ Wp,
                                            const float* __restrict__ bias, int act,
                                            char* xb, int l15, int q, int c0, int koff)
{
  f32x4 acc[4][4];
  #pragma unroll
  for (int a = 0; a < 4; ++a)
    #pragma unroll
    for (int b = 0; b < 4; ++b) { f32x4 z = {0.f, 0.f, 0.f, 0.f}; acc[a][b] = z; }

  const u16* Wl = Wp + (c0 + l15) * 32 + q * 8;   // lane's base within a K32 block

  if constexpr (NK == 1) {
    uint4 b0[4];
    #pragma unroll
    for (int ct = 0; ct < 4; ++ct)
      b0[ct] = *reinterpret_cast<const uint4*>(Wl + ct * 512);
    const int kb = q * 16;
    #pragma unroll
    for (int mt = 0; mt < 4; ++mt) {
      bf16x8 a = rdA(xb, mt * 16 + l15, kb);
      #pragma unroll
      for (int ct = 0; ct < 4; ++ct)
        acc[mt][ct] = __builtin_amdgcn_mfma_f32_16x16x32_bf16(
            a, __builtin_bit_cast(bf16x8, b0[ct]), acc[mt][ct], 0, 0, 0);
    }
  } else {
    uint4 bc[4], bn[4];
    {
      const u16* p = Wl + (size_t)koff * 16384;
      #pragma unroll
      for (int ct = 0; ct < 4; ++ct)
        bc[ct] = *reinterpret_cast<const uint4*>(p + ct * 512);
    }
    #pragma unroll 1
    for (int i = 0; i < NK; i += 2) {
      // prefetch step i+1
      {
        const int Kb = (i + 1) ^ koff;
        const u16* p = Wl + (size_t)Kb * 16384;
        #pragma unroll
        for (int ct = 0; ct < 4; ++ct)
          bn[ct] = *reinterpret_cast<const uint4*>(p + ct * 512);
      }
      // compute step i
      {
        const int kb = ((i ^ koff) * 64) + q * 16;
        #pragma unroll
        for (int mt = 0; mt < 4; ++mt) {
          bf16x8 a = rdA(xb, mt * 16 + l15, kb);
          #pragma unroll
          for (int ct = 0; ct < 4; ++ct)
            acc[mt][ct] = __builtin_amdgcn_mfma_f32_16x16x32_bf16(
                a, __builtin_bit_cast(bf16x8, bc[ct]), acc[mt][ct], 0, 0, 0);
        }
      }
      // prefetch step i+2 (wraps harmlessly on last iter)
      {
        const int Kc = ((i + 2) & (NK - 1)) ^ koff;
        const u16* p = Wl + (size_t)Kc * 16384;
        #pragma unroll
        for (int ct = 0; ct < 4; ++ct)
          bc[ct] = *reinterpret_cast<const uint4*>(p + ct * 512);
      }
      // compute step i+1
      {
        const int kb = (((i + 1) ^ koff) * 64) + q * 16;
        #pragma unroll
        for (int mt = 0; mt < 4; ++mt) {
          bf16x8 a = rdA(xb, mt * 16 + l15, kb);
          #pragma unroll
          for (int ct = 0; ct < 4; ++ct)
            acc[mt][ct] = __builtin_amdgcn_mfma_f32_16x16x32_bf16(
                a, __builtin_bit_cast(bf16x8, bn[ct]), acc[mt][ct], 0, 0, 0);
        }
      }
    }
  }
  __syncthreads();   // all waves done READING xs

  float bv[4];
  #pragma unroll
  for (int ct = 0; ct < 4; ++ct) bv[ct] = bias[c0 + ct * 16 + l15];
  #pragma unroll
  for (int mt = 0; mt < 4; ++mt)
    #pragma unroll
    for (int ct = 0; ct < 4; ++ct)
      #pragma unroll
      for (int j = 0; j < 4; ++j) {
        int row = mt * 16 + q * 4 + j;
        float z = acc[mt][ct][j] + bv[ct];
        float h = act ? fmaxf(z, 0.f) : z / (1.f + __expf(-z));
        st16(xb, row, c0 + ct * 16 + l15, f2bf(h));
      }
  __syncthreads();   // xs updated for next layer
}

template<int CN>
__global__ __launch_bounds__(512, 4) void fused_kernel(
    const float* __restrict__ T, const u16* __restrict__ wsu,
    const float* __restrict__ wsf, float* __restrict__ Xout, float* __restrict__ Xcout,
    float* __restrict__ errPart, int n_arg)
{
  const int n = CN ? CN : n_arg;
  __shared__ u16 xs[MT * 512];       // 64 KiB, XOR-swizzled
  __shared__ float xo[MT * 20];      // X_hat rows for distortion
  __shared__ float scaleS[MT];
  __shared__ float ered[8][2];

  const int tid = threadIdx.x;
  const int blk = blockIdx.x;
  const int lane = tid & 63;
  const int wid = tid >> 6;
  const int l15 = lane & 15;
  const int q = lane >> 4;           // 0..3
  const int c0 = wid * 64;           // wave's output-column base (hidden layers)
  const int koff = (blk >> 3) & 15;  // co-scheduled blocks on an XCD get distinct phases
  char* xb = (char*)xs;

  // ---- prologue: T load + normalize; 8 threads/row ----
  {
    const int r = tid >> 3, j = tid & 7;
    const size_t gr = (size_t)blk * MT + r;
    const float* tp = T + gr * n;
    const int k0 = 2 * j, k1 = 2 * j + 1;
    float v0 = (k0 < n) ? tp[k0] : 0.f;
    float v1 = (k1 < n) ? tp[k1] : 0.f;
    float ss = v0 * v0 + v1 * v1;
    ss += __shfl_xor(ss, 1); ss += __shfl_xor(ss, 2); ss += __shfl_xor(ss, 4);
    float norm = sqrtf(ss < 1e-12f ? 1e-12f : ss);
    float rn = 1.f / norm;
    if (j == 0) scaleS[r] = sqrtf(norm);
    st16(xb, r, k0, f2bf(v0 * rn));
    st16(xb, r, k1, f2bf(v1 * rn));
    st16(xb, r, 16 + k0, 0);
    st16(xb, r, 16 + k1, 0);
  }
  __syncthreads();

  dense_layer<1 >(wsu + WI_OFF,          wsf + BI_F,       0, xb, l15, q, c0, 0);
  dense_layer<16>(wsu + WH_OFF,          wsf + BH_F,       1, xb, l15, q, c0, koff);
  dense_layer<16>(wsu + WH_OFF + 262144, wsf + BH_F + 512, 1, xb, l15, q, c0, koff);

  // ---- output layer: waves 0..3, wave w owns rows w*16..+16, 32 padded cols ----
  if (wid < 4) {
    f32x4 oacc[2];
    { f32x4 z = {0.f, 0.f, 0.f, 0.f}; oacc[0] = z; oacc[1] = z; }
    const int bofs2 = l15 * 32 + q * 8;
    uint4 ob[2], on[2];
    #pragma unroll
    for (int ct = 0; ct < 2; ++ct)
      ob[ct] = *reinterpret_cast<const uint4*>(wsu + WO_OFF + bofs2 + ct * 512);
    #pragma unroll
    for (int K2 = 0; K2 < 16; K2 += 2) {
      #pragma unroll
      for (int ct = 0; ct < 2; ++ct)
        on[ct] = *reinterpret_cast<const uint4*>(wsu + WO_OFF + (K2 + 1) * 1024 + bofs2 + ct * 512);
      {
        bf16x8 a = rdA(xb, wid * 16 + l15, K2 * 64 + q * 16);
        #pragma unroll
        for (int ct = 0; ct < 2; ++ct)
          oacc[ct] = __builtin_amdgcn_mfma_f32_16x16x32_bf16(
              a, __builtin_bit_cast(bf16x8, ob[ct]), oacc[ct], 0, 0, 0);
      }
      if (K2 + 2 < 16) {
        #pragma unroll
        for (int ct = 0; ct < 2; ++ct)
          ob[ct] = *reinterpret_cast<const uint4*>(wsu + WO_OFF + (K2 + 2) * 1024 + bofs2 + ct * 512);
      }
      {
        bf16x8 a = rdA(xb, wid * 16 + l15, (K2 + 1) * 64 + q * 16);
        #pragma unroll
        for (int ct = 0; ct < 2; ++ct)
          oacc[ct] = __builtin_amdgcn_mfma_f32_16x16x32_bf16(
              a, __builtin_bit_cast(bf16x8, on[ct]), oacc[ct], 0, 0, 0);
      }
    }
    #pragma unroll
    for (int ct = 0; ct < 2; ++ct)
      #pragma unroll
      for (int j = 0; j < 4; ++j) {
        int o = ct * 16 + l15;
        int row = wid * 16 + q * 4 + j;
        if (o <= n) {
          float val = (oacc[ct][j] + wsf[BO_F + o]) * scaleS[row];
          size_t gr = (size_t)blk * MT + row;
          float cv = fminf(fmaxf(val, -2.f), 2.f);
          Xout[gr * (n + 1) + o] = val;
          Xcout[gr * (n + 1) + o] = cv;
          xo[row * 20 + o] = val;
        }
      }
  }
  __syncthreads();

  // ---- distortion + squared-error partials: 8 threads/row ----
  {
    const int r = tid >> 3, j = tid & 7;
    const size_t gr = (size_t)blk * MT + r;
    float x[17], cx[17];
    #pragma unroll
    for (int i = 0; i < 17; ++i) {
      float v = (i <= n) ? xo[r * 20 + i] : 0.f;
      x[i] = v; cx[i] = fminf(fmaxf(v, -2.f), 2.f);
    }
    float e = 0.f, ec = 0.f;
    #pragma unroll
    for (int kk = 0; kk < 2; ++kk) {
      int k = j + 1 + kk * 8;
      if (k <= n) {
        float d = 0.f, dc = 0.f;
        #pragma unroll
        for (int i = 0; i < 16; ++i) {
          if (i + k <= 16) {
            if (i + k <= n) { d += x[i] * x[i + k]; dc += cx[i] * cx[i + k]; }
          }
        }
        float tvv = T[gr * n + (n - k)];
        float r1 = d - tvv, r2 = dc - tvv;
        e += r1 * r1; ec += r2 * r2;
      }
    }
    e += __shfl_xor(e, 1);  ec += __shfl_xor(ec, 1);
    e += __shfl_xor(e, 2);  ec += __shfl_xor(ec, 2);
    e += __shfl_xor(e, 4);  ec += __shfl_xor(ec, 4);
    e += __shfl_xor(e, 8);  ec += __shfl_xor(ec, 8);
    e += __shfl_xor(e, 16); ec += __shfl_xor(ec, 16);
    e += __shfl_xor(e, 32); ec += __shfl_xor(ec, 32);
    if (lane == 0) { ered[wid][0] = e; ered[wid][1] = ec; }
  }
  __syncthreads();
  if (tid == 0) {
    float e = 0.f, ec = 0.f;
    #pragma unroll
    for (int w = 0; w < 8; ++w) { e += ered[w][0]; ec += ered[w][1]; }
    errPart[blk * 2]     = e;      // per-block partial (no global atomics)
    errPart[blk * 2 + 1] = ec;
  }
}

__global__ void finalize_kernel(const float* __restrict__ part, float* __restrict__ e0,
                                float* __restrict__ e1, float inv)
{
  __shared__ float se[4][2];
  const int t = threadIdx.x;           // 256 threads
  float e = 0.f, ec = 0.f;
  for (int b = t; b < BATCH / MT; b += 256) { e += part[2 * b]; ec += part[2 * b + 1]; }
  e += __shfl_xor(e, 1);  ec += __shfl_xor(ec, 1);
  e += __shfl_xor(e, 2);  ec += __shfl_xor(ec, 2);
  e += __shfl_xor(e, 4);  ec += __shfl_xor(ec, 4);
  e += __shfl_xor(e, 8);  ec += __shfl_xor(ec, 8);
  e += __shfl_xor(e, 16); ec += __shfl_xor(ec, 16);
  e += __shfl_xor(e, 32); ec += __shfl_xor(ec, 32);
  if ((t & 63) == 0) { se[t >> 6][0] = e; se[t >> 6][1] = ec; }
  __syncthreads();
  if (t == 0) {
    float te = 0.f, tec = 0.f;
    #pragma unroll
    for (int w = 0; w < 4; ++w) { te += se[w][0]; tec += se[w][1]; }
    e0[0] = te * inv;
    e1[0] = tec * inv;
  }
}

extern "C" void kernel_launch(void* const* d_in, const int* in_sizes, int n_in,
                              void* d_out, int out_size, void* d_ws, size_t ws_size,
                              hipStream_t stream)
{
  const float* T       = (const float*)d_in[0];
  const int*   variant = (const int*)d_in[2];
  const float* w_in    = (const float*)d_in[3];
  const float* b_in    = (const float*)d_in[4];
  const float* w_hid   = (const float*)d_in[5];
  const float* b_hid   = (const float*)d_in[6];
  const float* w_out   = (const float*)d_in[7];
  const float* b_out   = (const float*)d_in[8];
  const int n = in_sizes[0] / BATCH;

  u16* wsu = (u16*)d_ws;
  float* wsf = (float*)((char*)d_ws + (size_t)WS_USH * 2);
  float* out = (float*)d_out;
  const size_t xe = (size_t)BATCH * (n + 1);
  float* Xo  = out;
  float* eP  = out + xe;
  float* Xc  = out + xe + 1;
  float* ecP = out + 2 * xe + 1;

  const int prepBlocks = (PREP_TOTAL + 255) / 256;
  prep_kernel<<<prepBlocks, 256, 0, stream>>>(w_in, b_in, w_hid, b_hid, w_out, b_out,
                                              variant, n, wsu, wsf);
  if (n == 16)
    fused_kernel<16><<<BATCH / MT, 512, 0, stream>>>(T, wsu, wsf, Xo, Xc, wsf + PART_F, n);
  else
    fused_kernel<0><<<BATCH / MT, 512, 0, stream>>>(T, wsu, wsf, Xo, Xc, wsf + PART_F, n);
  finalize_kernel<<<1, 256, 0, stream>>>(wsf + PART_F, eP, ecP, 1.f / (float)((size_t)BATCH * n));
}

// Round 6
// 135.631 us; speedup vs baseline: 1.4058x; 1.0734x over previous
//
#include <hip/hip_runtime.h>

#define BATCH 65536
#define MT 128                // rows per block (2 panels of 64)
#define NBLK (BATCH / MT)     // 512

typedef unsigned short u16;
typedef __bf16 bf16x8 __attribute__((ext_vector_type(8)));
typedef float f32x4 __attribute__((ext_vector_type(4)));

// d_ws layout (u16 element offsets) — fragment-native weight layouts:
//   W'[K32][col][g][e]: element (col, k) at [K32][col][k>>3 & 3][k&7], k = K32*32+g*8+e
#define WI_OFF 0              // [1][512][4][8]   (k>=16 zero)
#define WH_OFF 16384          // [2][16][512][4][8]
#define WO_OFF 540672         // [16][32][4][8]   (cols o padded 17->32)
#define WS_USH 557056
// float region at (char*)ws + WS_USH*2
#define BI_F 0
#define BH_F 512
#define BO_F 1536
#define PART_F 1568           // [NBLK][2] per-block error partials
#define PREP_WH 65536
#define PREP_WI 2048
#define PREP_WO 2048
#define PREP_SC 1568
#define PREP_TOTAL (PREP_WH + PREP_WI + PREP_WO + PREP_SC)

__device__ inline u16 f2bf(float f) {
  union { float f; unsigned u; } v; v.f = f;
  unsigned u = v.u + 0x7fffu + ((v.u >> 16) & 1u);   // RNE
  return (u16)(u >> 16);
}

__global__ void prep_kernel(const float* __restrict__ w_in, const float* __restrict__ b_in,
                            const float* __restrict__ w_hid, const float* __restrict__ b_hid,
                            const float* __restrict__ w_out, const float* __restrict__ b_out,
                            const int* __restrict__ variant, int n,
                            u16* __restrict__ wsu, float* __restrict__ wsf)
{
  const int model = (n - 5) * 16 + variant[0];
  const int i = blockIdx.x * 256 + threadIdx.x;
  if (i < PREP_WH) {
    int g = i & 3, col = (i >> 2) & 511, K32 = (i >> 11) & 15, l = i >> 15;
    const float* src = w_hid + (size_t)model * 524288 + (size_t)l * 262144 + col * 512 + K32 * 32 + g * 8;
    u16* dst = wsu + WH_OFF + (size_t)i * 8;
    #pragma unroll
    for (int e = 0; e < 8; ++e) dst[e] = f2bf(src[e]);
  } else if (i < PREP_WH + PREP_WI) {
    int j = i - PREP_WH;
    int g = j & 3, col = j >> 2;
    u16* dst = wsu + WI_OFF + (size_t)j * 8;
    #pragma unroll
    for (int e = 0; e < 8; ++e) {
      int k = g * 8 + e;
      dst[e] = (k < 16) ? f2bf(w_in[(size_t)model * 8192 + col * 16 + k]) : (u16)0;
    }
  } else if (i < PREP_WH + PREP_WI + PREP_WO) {
    int j = i - PREP_WH - PREP_WI;
    int g = j & 3, col = (j >> 2) & 31, K32 = j >> 7;
    u16* dst = wsu + WO_OFF + (size_t)j * 8;
    #pragma unroll
    for (int e = 0; e < 8; ++e) {
      int k = K32 * 32 + g * 8 + e;
      dst[e] = (col < 17) ? f2bf(w_out[(size_t)model * 8704 + col * 512 + k]) : (u16)0;
    }
  } else if (i < PREP_TOTAL) {
    int j = i - PREP_WH - PREP_WI - PREP_WO;
    if (j < 512)       wsf[BI_F + j] = b_in[(size_t)model * 512 + j];
    else if (j < 1536) wsf[BH_F + (j - 512)] = b_hid[(size_t)model * 1024 + (j - 512)];
    else               { int o = j - 1536; wsf[BO_F + o] = (o < 17) ? b_out[(size_t)model * 17 + o] : 0.f; }
  }
}

// xs layout: byte = row*1024 + ((col*2) ^ ((row&15)<<4))
__device__ __forceinline__ bf16x8 rdA(const char* xb, int row, int kbyte) {
  return *reinterpret_cast<const bf16x8*>(xb + row * 1024 + (kbyte ^ ((row & 15) << 4)));
}
__device__ __forceinline__ void st16(char* xb, int row, int col, u16 v) {
  *(u16*)(xb + row * 1024 + ((col * 2) ^ ((row & 15) << 4))) = v;
}

// One dense layer over BOTH 64-row panels: wave computes rows [0,128) x cols [c0,c0+64).
// Every B-fragment is loaded once and applied to both panels (halves weight traffic).
// NK: compile-time K32 step count. koff: per-block K-phase (XOR stagger). act: 0=silu 1=relu.
template<int NK>
__device__ __forceinline__ void dense_layer(const u16* __restrict__ Wp,
                                            const float* __restrict__ bias, int act,
                                            char* xb, int l15, int q, int c0, int koff)
{
  f32x4 acc[2][4][4];
  #pragma unroll
  for (int p = 0; p < 2; ++p)
    #pragma unroll
    for (int a = 0; a < 4; ++a)
      #pragma unroll
      for (int b = 0; b < 4; ++b) { f32x4 z = {0.f, 0.f, 0.f, 0.f}; acc[p][a][b] = z; }

  const u16* Wl = Wp + (c0 + l15) * 32 + q * 8;   // lane's base within a K32 block

  if constexpr (NK == 1) {
    uint4 b0[4];
    #pragma unroll
    for (int ct = 0; ct < 4; ++ct)
      b0[ct] = *reinterpret_cast<const uint4*>(Wl + ct * 512);
    const int kb = q * 16;
    #pragma unroll
    for (int p = 0; p < 2; ++p)
      #pragma unroll
      for (int mt = 0; mt < 4; ++mt) {
        bf16x8 a = rdA(xb, p * 64 + mt * 16 + l15, kb);
        #pragma unroll
        for (int ct = 0; ct < 4; ++ct)
          acc[p][mt][ct] = __builtin_amdgcn_mfma_f32_16x16x32_bf16(
              a, __builtin_bit_cast(bf16x8, b0[ct]), acc[p][mt][ct], 0, 0, 0);
      }
  } else {
    uint4 bc[4], bn[4];
    {
      const u16* p = Wl + (size_t)koff * 16384;
      #pragma unroll
      for (int ct = 0; ct < 4; ++ct)
        bc[ct] = *reinterpret_cast<const uint4*>(p + ct * 512);
    }
    #pragma unroll 1
    for (int i = 0; i < NK; i += 2) {
      // prefetch step i+1
      {
        const int Kb = (i + 1) ^ koff;
        const u16* p = Wl + (size_t)Kb * 16384;
        #pragma unroll
        for (int ct = 0; ct < 4; ++ct)
          bn[ct] = *reinterpret_cast<const uint4*>(p + ct * 512);
      }
      // compute step i with bc (both panels share B)
      {
        const int kb = ((i ^ koff) * 64) + q * 16;
        #pragma unroll
        for (int p = 0; p < 2; ++p)
          #pragma unroll
          for (int mt = 0; mt < 4; ++mt) {
            bf16x8 a = rdA(xb, p * 64 + mt * 16 + l15, kb);
            #pragma unroll
            for (int ct = 0; ct < 4; ++ct)
              acc[p][mt][ct] = __builtin_amdgcn_mfma_f32_16x16x32_bf16(
                  a, __builtin_bit_cast(bf16x8, bc[ct]), acc[p][mt][ct], 0, 0, 0);
          }
      }
      // prefetch step i+2 (wraps harmlessly on last iter)
      {
        const int Kc = ((i + 2) & (NK - 1)) ^ koff;
        const u16* p = Wl + (size_t)Kc * 16384;
        #pragma unroll
        for (int ct = 0; ct < 4; ++ct)
          bc[ct] = *reinterpret_cast<const uint4*>(p + ct * 512);
      }
      // compute step i+1 with bn
      {
        const int kb = (((i + 1) ^ koff) * 64) + q * 16;
        #pragma unroll
        for (int p = 0; p < 2; ++p)
          #pragma unroll
          for (int mt = 0; mt < 4; ++mt) {
            bf16x8 a = rdA(xb, p * 64 + mt * 16 + l15, kb);
            #pragma unroll
            for (int ct = 0; ct < 4; ++ct)
              acc[p][mt][ct] = __builtin_amdgcn_mfma_f32_16x16x32_bf16(
                  a, __builtin_bit_cast(bf16x8, bn[ct]), acc[p][mt][ct], 0, 0, 0);
          }
      }
    }
  }
  __syncthreads();   // all waves done READING xs

  float bv[4];
  #pragma unroll
  for (int ct = 0; ct < 4; ++ct) bv[ct] = bias[c0 + ct * 16 + l15];
  #pragma unroll
  for (int p = 0; p < 2; ++p)
    #pragma unroll
    for (int mt = 0; mt < 4; ++mt)
      #pragma unroll
      for (int ct = 0; ct < 4; ++ct)
        #pragma unroll
        for (int j = 0; j < 4; ++j) {
          int row = p * 64 + mt * 16 + q * 4 + j;
          float z = acc[p][mt][ct][j] + bv[ct];
          float h = act ? fmaxf(z, 0.f) : z / (1.f + __expf(-z));
          st16(xb, row, c0 + ct * 16 + l15, f2bf(h));
        }
  __syncthreads();   // xs updated for next layer
}

template<int CN>
__global__ __launch_bounds__(512, 2) void fused_kernel(
    const float* __restrict__ T, const u16* __restrict__ wsu,
    const float* __restrict__ wsf, float* __restrict__ Xout, float* __restrict__ Xcout,
    float* __restrict__ errPart, int n_arg)
{
  const int n = CN ? CN : n_arg;
  __shared__ u16 xs[MT * 512];       // 128 KiB, XOR-swizzled
  __shared__ float xo[MT * 20];      // X_hat rows for distortion (10 KiB)
  __shared__ float scaleS[MT];
  __shared__ float ered[8][2];

  const int tid = threadIdx.x;
  const int blk = blockIdx.x;
  const int lane = tid & 63;
  const int wid = tid >> 6;          // 0..7
  const int l15 = lane & 15;
  const int q = lane >> 4;           // 0..3
  const int c0 = wid * 64;           // wave's output-column base (hidden layers)
  const int koff = (blk >> 3) & 15;  // co-scheduled blocks on an XCD get distinct phases
  char* xb = (char*)xs;

  // ---- prologue: T load + normalize; 4 threads/row ----
  {
    const int r = tid >> 2, j = tid & 3;
    const size_t gr = (size_t)blk * MT + r;
    const float* tp = T + gr * n;
    float v[4]; float ss = 0.f;
    #pragma unroll
    for (int c = 0; c < 4; ++c) {
      int k = j * 4 + c;
      v[c] = (k < n) ? tp[k] : 0.f;
      ss += v[c] * v[c];
    }
    ss += __shfl_xor(ss, 1); ss += __shfl_xor(ss, 2);
    float norm = sqrtf(ss < 1e-12f ? 1e-12f : ss);
    float rn = 1.f / norm;
    if (j == 0) scaleS[r] = sqrtf(norm);
    #pragma unroll
    for (int c = 0; c < 4; ++c) {
      st16(xb, r, j * 4 + c, f2bf(v[c] * rn));
      st16(xb, r, 16 + j * 4 + c, 0);
    }
  }
  __syncthreads();

  dense_layer<1 >(wsu + WI_OFF,          wsf + BI_F,       0, xb, l15, q, c0, 0);
  dense_layer<16>(wsu + WH_OFF,          wsf + BH_F,       1, xb, l15, q, c0, koff);
  dense_layer<16>(wsu + WH_OFF + 262144, wsf + BH_F + 512, 1, xb, l15, q, c0, koff);

  // ---- output layer: 8 waves, wave w owns rows w*16..+16, 32 padded cols ----
  {
    f32x4 oacc[2];
    { f32x4 z = {0.f, 0.f, 0.f, 0.f}; oacc[0] = z; oacc[1] = z; }
    const int bofs2 = l15 * 32 + q * 8;
    uint4 ob[2], on[2];
    #pragma unroll
    for (int ct = 0; ct < 2; ++ct)
      ob[ct] = *reinterpret_cast<const uint4*>(wsu + WO_OFF + bofs2 + ct * 512);
    #pragma unroll
    for (int K2 = 0; K2 < 16; K2 += 2) {
      #pragma unroll
      for (int ct = 0; ct < 2; ++ct)
        on[ct] = *reinterpret_cast<const uint4*>(wsu + WO_OFF + (K2 + 1) * 1024 + bofs2 + ct * 512);
      {
        bf16x8 a = rdA(xb, wid * 16 + l15, K2 * 64 + q * 16);
        #pragma unroll
        for (int ct = 0; ct < 2; ++ct)
          oacc[ct] = __builtin_amdgcn_mfma_f32_16x16x32_bf16(
              a, __builtin_bit_cast(bf16x8, ob[ct]), oacc[ct], 0, 0, 0);
      }
      if (K2 + 2 < 16) {
        #pragma unroll
        for (int ct = 0; ct < 2; ++ct)
          ob[ct] = *reinterpret_cast<const uint4*>(wsu + WO_OFF + (K2 + 2) * 1024 + bofs2 + ct * 512);
      }
      {
        bf16x8 a = rdA(xb, wid * 16 + l15, (K2 + 1) * 64 + q * 16);
        #pragma unroll
        for (int ct = 0; ct < 2; ++ct)
          oacc[ct] = __builtin_amdgcn_mfma_f32_16x16x32_bf16(
              a, __builtin_bit_cast(bf16x8, on[ct]), oacc[ct], 0, 0, 0);
      }
    }
    #pragma unroll
    for (int ct = 0; ct < 2; ++ct)
      #pragma unroll
      for (int j = 0; j < 4; ++j) {
        int o = ct * 16 + l15;
        int row = wid * 16 + q * 4 + j;
        if (o <= n) {
          float val = (oacc[ct][j] + wsf[BO_F + o]) * scaleS[row];
          size_t gr = (size_t)blk * MT + row;
          float cv = fminf(fmaxf(val, -2.f), 2.f);
          Xout[gr * (n + 1) + o] = val;
          Xcout[gr * (n + 1) + o] = cv;
          xo[row * 20 + o] = val;
        }
      }
  }
  __syncthreads();

  // ---- distortion + squared-error partials: 4 threads/row ----
  {
    const int r = tid >> 2, j = tid & 3;
    const size_t gr = (size_t)blk * MT + r;
    float x[17], cx[17];
    #pragma unroll
    for (int i = 0; i < 17; ++i) {
      float v = (i <= n) ? xo[r * 20 + i] : 0.f;
      x[i] = v; cx[i] = fminf(fmaxf(v, -2.f), 2.f);
    }
    float e = 0.f, ec = 0.f;
    #pragma unroll
    for (int kk = 0; kk < 4; ++kk) {
      int k = j + 1 + kk * 4;
      if (k <= n) {
        float d = 0.f, dc = 0.f;
        #pragma unroll
        for (int i = 0; i < 16; ++i) {
          if (i + k <= 16) {
            if (i + k <= n) { d += x[i] * x[i + k]; dc += cx[i] * cx[i + k]; }
          }
        }
        float tvv = T[gr * n + (n - k)];
        float r1 = d - tvv, r2 = dc - tvv;
        e += r1 * r1; ec += r2 * r2;
      }
    }
    // reduce within row (4 lanes) then across the wave's 16 rows
    e += __shfl_xor(e, 1);  ec += __shfl_xor(ec, 1);
    e += __shfl_xor(e, 2);  ec += __shfl_xor(ec, 2);
    e += __shfl_xor(e, 4);  ec += __shfl_xor(ec, 4);
    e += __shfl_xor(e, 8);  ec += __shfl_xor(ec, 8);
    e += __shfl_xor(e, 16); ec += __shfl_xor(ec, 16);
    e += __shfl_xor(e, 32); ec += __shfl_xor(ec, 32);
    if (lane == 0) { ered[wid][0] = e; ered[wid][1] = ec; }
  }
  __syncthreads();
  if (tid == 0) {
    float e = 0.f, ec = 0.f;
    #pragma unroll
    for (int w = 0; w < 8; ++w) { e += ered[w][0]; ec += ered[w][1]; }
    errPart[blk * 2]     = e;      // per-block partial (no global atomics)
    errPart[blk * 2 + 1] = ec;
  }
}

__global__ void finalize_kernel(const float* __restrict__ part, float* __restrict__ e0,
                                float* __restrict__ e1, float inv)
{
  __shared__ float se[4][2];
  const int t = threadIdx.x;           // 256 threads
  float e = 0.f, ec = 0.f;
  for (int b = t; b < NBLK; b += 256) { e += part[2 * b]; ec += part[2 * b + 1]; }
  e += __shfl_xor(e, 1);  ec += __shfl_xor(ec, 1);
  e += __shfl_xor(e, 2);  ec += __shfl_xor(ec, 2);
  e += __shfl_xor(e, 4);  ec += __shfl_xor(ec, 4);
  e += __shfl_xor(e, 8);  ec += __shfl_xor(ec, 8);
  e += __shfl_xor(e, 16); ec += __shfl_xor(ec, 16);
  e += __shfl_xor(e, 32); ec += __shfl_xor(ec, 32);
  if ((t & 63) == 0) { se[t >> 6][0] = e; se[t >> 6][1] = ec; }
  __syncthreads();
  if (t == 0) {
    float te = 0.f, tec = 0.f;
    #pragma unroll
    for (int w = 0; w < 4; ++w) { te += se[w][0]; tec += se[w][1]; }
    e0[0] = te * inv;
    e1[0] = tec * inv;
  }
}

extern "C" void kernel_launch(void* const* d_in, const int* in_sizes, int n_in,
                              void* d_out, int out_size, void* d_ws, size_t ws_size,
                              hipStream_t stream)
{
  const float* T       = (const float*)d_in[0];
  const int*   variant = (const int*)d_in[2];
  const float* w_in    = (const float*)d_in[3];
  const float* b_in    = (const float*)d_in[4];
  const float* w_hid   = (const float*)d_in[5];
  const float* b_hid   = (const float*)d_in[6];
  const float* w_out   = (const float*)d_in[7];
  const float* b_out   = (const float*)d_in[8];
  const int n = in_sizes[0] / BATCH;

  u16* wsu = (u16*)d_ws;
  float* wsf = (float*)((char*)d_ws + (size_t)WS_USH * 2);
  float* out = (float*)d_out;
  const size_t xe = (size_t)BATCH * (n + 1);
  float* Xo  = out;
  float* eP  = out + xe;
  float* Xc  = out + xe + 1;
  float* ecP = out + 2 * xe + 1;

  const int prepBlocks = (PREP_TOTAL + 255) / 256;
  prep_kernel<<<prepBlocks, 256, 0, stream>>>(w_in, b_in, w_hid, b_hid, w_out, b_out,
                                              variant, n, wsu, wsf);
  if (n == 16)
    fused_kernel<16><<<NBLK, 512, 0, stream>>>(T, wsu, wsf, Xo, Xc, wsf + PART_F, n);
  else
    fused_kernel<0><<<NBLK, 512, 0, stream>>>(T, wsu, wsf, Xo, Xc, wsf + PART_F, n);
  finalize_kernel<<<1, 256, 0, stream>>>(wsf + PART_F, eP, ecP, 1.f / (float)((size_t)BATCH * n));
}